// Round 7
// baseline (165.001 us; speedup 1.0000x reference)
//
#include <hip/hip_runtime.h>
#include <hip/hip_bf16.h>

#define H0 200
#define W0 304
#define H1 100
#define W1 152
#define H2 50
#define W2 76
#define CPL 256   // channels per level
#define CTOT 768
#define OH 7
#define OW 7
#define NPOS 49

#define P0 (H0*W0)   // 60800
#define P1 (H1*W1)   // 15200
#define P2 (H2*W2)   // 3800
#define T0_OFF ((size_t)0)
#define T1_OFF ((size_t)P0*CPL)
#define T2_OFF ((size_t)P0*CPL + (size_t)P1*CPL)
#define WS_ELEMS ((size_t)P0*CPL + (size_t)P1*CPL + (size_t)P2*CPL)
#define WS_BYTES (WS_ELEMS * 2)   // bf16 workspace: 40,857,600 B

__device__ __forceinline__ float hat01(float d) {
    return fmaxf(0.0f, 1.0f - fabsf(d));
}

__device__ __forceinline__ unsigned short f2bf_rne(float x) {
    unsigned int u = __float_as_uint(x);
    u += 0x7fffu + ((u >> 16) & 1u);
    return (unsigned short)(u >> 16);
}

// ------------- Stage 1: fused [C][P] fp32 -> [P][C] bf16 transpose ----------
// 64p x 64c tile; float4 loads along p, 16B (uint4 = 8 bf16) stores along c.
// tile row stride = 72 ushort = 9 x 16B (odd multiple -> low-conflict b128).
__global__ void __launch_bounds__(256)
transpose_all_kernel(const float* __restrict__ f0, const float* __restrict__ f1,
                     const float* __restrict__ f2,
                     unsigned short* __restrict__ T0,
                     unsigned short* __restrict__ T1,
                     unsigned short* __restrict__ T2, int n0, int n01) {
    __shared__ unsigned short tile[64][72];   // [p_local][c_local]
    int b = blockIdx.x;
    const float* in; unsigned short* outp; int P; int rel;
    if (b < n0)       { in = f0; outp = T0; P = P0; rel = b; }
    else if (b < n01) { in = f1; outp = T1; P = P1; rel = b - n0; }
    else              { in = f2; outp = T2; P = P2; rel = b - n01; }
    int p0 = (rel >> 2) * 64;
    int c0 = (rel & 3) * 64;

    int q = threadIdx.x & 15;     // p-quad
    int r = threadIdx.x >> 4;     // 0..15 (c)
    bool full = (p0 + 64 <= P);
#pragma unroll
    for (int i = 0; i < 4; ++i) {
        int c = c0 + r + 16 * i;
        int p = p0 + 4 * q;
        float4 v;
        if (full) {
            v = *(const float4*)(in + (size_t)c * P + p);
        } else {
            v.x = (p + 0 < P) ? in[(size_t)c * P + p + 0] : 0.0f;
            v.y = (p + 1 < P) ? in[(size_t)c * P + p + 1] : 0.0f;
            v.z = (p + 2 < P) ? in[(size_t)c * P + p + 2] : 0.0f;
            v.w = (p + 3 < P) ? in[(size_t)c * P + p + 3] : 0.0f;
        }
        tile[4 * q + 0][r + 16 * i] = f2bf_rne(v.x);
        tile[4 * q + 1][r + 16 * i] = f2bf_rne(v.y);
        tile[4 * q + 2][r + 16 * i] = f2bf_rne(v.z);
        tile[4 * q + 3][r + 16 * i] = f2bf_rne(v.w);
    }
    __syncthreads();
    // store phase: 16B per lane. 8 lanes cover 64 channels; 32 rows per iter.
    int q8 = threadIdx.x & 7;     // c-octet
    int r8 = threadIdx.x >> 3;    // 0..31 (p)
#pragma unroll
    for (int i = 0; i < 2; ++i) {
        int p = p0 + r8 + 32 * i;
        if (p < P) {
            uint4 w = *(const uint4*)&tile[r8 + 32 * i][8 * q8];
            *(uint4*)(outp + (size_t)p * CPL + c0 + 8 * q8) = w;
        }
    }
}

// ------------- Stage 2: channels-last RoIAlign, bf16x4 per lane -------------
// Compile-time tap loops selected per pos by wave-uniform branches on the
// actual per-axis window counts (typical 4, padded max 6/5).
template<int TY, int TX>
__device__ __forceinline__ float4 accum_pos(const unsigned short* __restrict__ Tc,
                                            const int* yi, const float* yw,
                                            const int* xi, const float* xw) {
    float a0 = 0.0f, a1 = 0.0f, a2 = 0.0f, a3 = 0.0f;
#pragma unroll
    for (int a = 0; a < TY; ++a) {
        float s0 = 0.0f, s1 = 0.0f, s2 = 0.0f, s3 = 0.0f;
#pragma unroll
        for (int b = 0; b < TX; ++b) {
            uint2 v = *(const uint2*)(Tc + (unsigned)(yi[a] + xi[b]));
            float wxb = xw[b];
            s0 += wxb * __uint_as_float(v.x << 16);
            s1 += wxb * __uint_as_float(v.x & 0xffff0000u);
            s2 += wxb * __uint_as_float(v.y << 16);
            s3 += wxb * __uint_as_float(v.y & 0xffff0000u);
        }
        a0 += yw[a] * s0; a1 += yw[a] * s1; a2 += yw[a] * s2; a3 += yw[a] * s3;
    }
    float4 r;
    r.x = a0 * 0.25f; r.y = a1 * 0.25f; r.z = a2 * 0.25f; r.w = a3 * 0.25f;
    return r;
}

// MAXT = padded max taps per axis for this level; branches pick 4 vs MAXT.
template<int MAXT>
__device__ __forceinline__ void run_level_dyn(const unsigned short* __restrict__ Tc,
                                              const int* s_cnt,
                                              const int (*s_idx)[6], const float (*s_w)[6],
                                              float (*sout)[260], int wv, int coff) {
    for (int pos = wv; pos < NPOS; pos += 8) {
        int oh = pos / 7;
        int ow = pos - oh * 7;
        int yi[6], xi[6];
        float yw[6], xw[6];
#pragma unroll
        for (int j = 0; j < 6; ++j) {
            yi[j] = s_idx[oh][j];     yw[j] = s_w[oh][j];
            xi[j] = s_idx[7 + ow][j]; xw[j] = s_w[7 + ow][j];
        }
        bool y4 = s_cnt[oh] <= 4;
        bool x4 = s_cnt[7 + ow] <= 4;
        float4 res;
        if (y4) {
            if (x4) res = accum_pos<4, 4>(Tc, yi, yw, xi, xw);
            else    res = accum_pos<4, MAXT>(Tc, yi, yw, xi, xw);
        } else {
            if (x4) res = accum_pos<MAXT, 4>(Tc, yi, yw, xi, xw);
            else    res = accum_pos<MAXT, MAXT>(Tc, yi, yw, xi, xw);
        }
        *(float4*)&sout[pos][coff] = res;
    }
}

__device__ __forceinline__ void run_level_l0(const unsigned short* __restrict__ Tc,
                                             const int (*s_idx)[6], const float (*s_w)[6],
                                             float (*sout)[260], int wv, int coff) {
    for (int pos = wv; pos < NPOS; pos += 8) {
        int oh = pos / 7;
        int ow = pos - oh * 7;
        int yi[4], xi[4];
        float yw[4], xw[4];
#pragma unroll
        for (int j = 0; j < 4; ++j) {
            yi[j] = s_idx[oh][j];     yw[j] = s_w[oh][j];
            xi[j] = s_idx[7 + ow][j]; xw[j] = s_w[7 + ow][j];
        }
        float4 res = accum_pos<4, 4>(Tc, yi, yw, xi, xw);
        *(float4*)&sout[pos][coff] = res;
    }
}

__global__ void __launch_bounds__(512)
roi_align_cl5_kernel(const unsigned short* __restrict__ T0,
                     const unsigned short* __restrict__ T1,
                     const unsigned short* __restrict__ T2,
                     const float* __restrict__ boxes,
                     const int* __restrict__ img_h_p,
                     const int* __restrict__ img_w_p,
                     float* __restrict__ out) {
    __shared__ float sout[NPOS][260];
    __shared__ int   s_cnt[14];
    __shared__ int   s_idx[14][6];
    __shared__ float s_w[14][6];

    int n = blockIdx.x;
    int level = blockIdx.y;
    const unsigned short* T; int Hc, Wc; float inv_s;
    if (level == 0)      { T = T0; Hc = H0; Wc = W0; inv_s = 1.0f;  }
    else if (level == 1) { T = T1; Hc = H1; Wc = W1; inv_s = 0.5f;  }
    else                 { T = T2; Hc = H2; Wc = W2; inv_s = 0.25f; }

    int tid = threadIdx.x;
    if (tid < 14) {
        int axis = (tid >= 7) ? 1 : 0;   // 0 = y, 1 = x
        int o = tid - axis * 7;
        float sx = (float)W0 / (float)img_w_p[0];
        float sy = (float)H0 / (float)img_h_p[0];
        float a1, bs; int Hf, Hca, mul;
        if (axis) {
            a1 = boxes[n * 4 + 0] * sx;
            float a2 = boxes[n * 4 + 2] * sx;
            bs = fmaxf(a2 - a1, 1.0f) * (1.0f / (float)OW);
            Hf = W0; Hca = Wc; mul = 1;
        } else {
            a1 = boxes[n * 4 + 1] * sy;
            float a2 = boxes[n * 4 + 3] * sy;
            bs = fmaxf(a2 - a1, 1.0f) * (1.0f / (float)OH);
            Hf = H0; Hca = Hc; mul = Wc;
        }
        int cnt = 4;
        int idx[6]; float w[6];
#pragma unroll
        for (int j = 0; j < 6; ++j) { idx[j] = 0; w[j] = 0.0f; }
        if (level == 0) {
#pragma unroll
            for (int r2 = 0; r2 < 2; ++r2) {
                float Y = a1 + ((float)o + 0.25f + 0.5f * (float)r2) * bs;
                float v = (Y >= -1.0f && Y <= (float)Hf) ? 1.0f : 0.0f;
                float Yc = fminf(fmaxf(Y, 0.0f), (float)(Hf - 1));
                int y0 = (int)Yc; float lf = Yc - (float)y0;
                idx[2 * r2]     = y0;                  w[2 * r2]     = (1.0f - lf) * v;
                idx[2 * r2 + 1] = min(y0 + 1, Hf - 1); w[2 * r2 + 1] = lf * v;
            }
        } else {
            int bases[2]; float w3[2][3];
#pragma unroll
            for (int r2 = 0; r2 < 2; ++r2) {
                float Y = a1 + ((float)o + 0.25f + 0.5f * (float)r2) * bs;
                float v = (Y >= -1.0f && Y <= (float)Hf) ? 1.0f : 0.0f;
                float Yc = fminf(fmaxf(Y, 0.0f), (float)(Hf - 1));
                int y0 = (int)Yc; float lf = Yc - (float)y0; float hf = 1.0f - lf;
                int yf1 = min(y0 + 1, Hf - 1);
                float yc0 = fminf(fmaxf(((float)y0 + 0.5f) * inv_s - 0.5f, 0.0f), (float)(Hca - 1));
                float yc1 = fminf(fmaxf(((float)yf1 + 0.5f) * inv_s - 0.5f, 0.0f), (float)(Hca - 1));
                int b2 = (int)yc0;
                bases[r2] = b2;
#pragma unroll
                for (int t2 = 0; t2 < 3; ++t2) {
                    float j2 = (float)(b2 + t2);
                    w3[r2][t2] = v * (hf * hat01(yc0 - j2) + lf * hat01(yc1 - j2));
                }
            }
            int dmax = (level == 1) ? 3 : 2;   // geometry: box<=272px -> gap<=2.43/1.21
            int d = min(max(bases[1] - bases[0], 0), dmax);
            cnt = d + 3;
            w[0] += w3[0][0]; w[1] += w3[0][1]; w[2] += w3[0][2];
            w[d] += w3[1][0]; w[d + 1] += w3[1][1]; w[d + 2] += w3[1][2];
#pragma unroll
            for (int j = 0; j < 6; ++j) idx[j] = min(bases[0] + j, Hca - 1);
        }
        s_cnt[tid] = cnt;
        // pre-scale to element offset (row stride incl. CPL; col stride = CPL)
#pragma unroll
        for (int j = 0; j < 6; ++j) { s_idx[tid][j] = idx[j] * mul * CPL; s_w[tid][j] = w[j]; }
    }
    __syncthreads();

    int lane = tid & 63;
    int wv = tid >> 6;                 // 0..7
    int coff = lane * 4;               // channel offset within level
    const unsigned short* Tc = T + coff;

    if (level == 0)      run_level_l0(Tc, s_idx, s_w, sout, wv, coff);
    else if (level == 1) run_level_dyn<6>(Tc, s_cnt, s_idx, s_w, sout, wv, coff);
    else                 run_level_dyn<5>(Tc, s_cnt, s_idx, s_w, sout, wv, coff);
    __syncthreads();

    size_t obase = ((size_t)n * CTOT + (size_t)level * CPL) * NPOS;
    for (int i2 = tid; i2 < CPL * NPOS; i2 += 512) {
        int c = i2 / NPOS;
        int p = i2 - c * NPOS;
        out[obase + i2] = sout[p][c];
    }
}

// ---------------- Fallback (R1 kernel) if ws too small ----------------------
__device__ __forceinline__ void axis_w3_fb(int yf0, int Hf, int Hc, float inv_s,
                                           float lf, int& base, float* w) {
    int yf1 = min(yf0 + 1, Hf - 1);
    float hf = 1.0f - lf;
    float yc0 = fminf(fmaxf(((float)yf0 + 0.5f) * inv_s - 0.5f, 0.0f), (float)(Hc - 1));
    float yc1 = fminf(fmaxf(((float)yf1 + 0.5f) * inv_s - 0.5f, 0.0f), (float)(Hc - 1));
    base = (int)yc0;
#pragma unroll
    for (int r = 0; r < 3; ++r) {
        float j = (float)(base + r);
        w[r] = hf * hat01(yc0 - j) + lf * hat01(yc1 - j);
    }
}

__global__ void __launch_bounds__(256)
roi_align_fused_fb_kernel(const float* __restrict__ f0,
                          const float* __restrict__ f1,
                          const float* __restrict__ f2,
                          const float* __restrict__ boxes,
                          const int* __restrict__ img_h_p,
                          const int* __restrict__ img_w_p,
                          float* __restrict__ out,
                          int total) {
    int i = blockIdx.x * blockDim.x + threadIdx.x;
    if (i >= total) return;
    int ow = i % OW;
    int t = i / OW;
    int oh = t % OH; t /= OH;
    int c = t % CTOT;
    int n = t / CTOT;
    float sx = (float)W0 / (float)img_w_p[0];
    float sy = (float)H0 / (float)img_h_p[0];
    float bx1 = boxes[n * 4 + 0] * sx;
    float by1 = boxes[n * 4 + 1] * sy;
    float bw = fmaxf(boxes[n * 4 + 2] * sx - bx1, 1.0f) / OW;
    float bh = fmaxf(boxes[n * 4 + 3] * sy - by1, 1.0f) / OH;
    int level = c >> 8;
    int cl = c & (CPL - 1);
    const float* f;
    int Hc, Wc; float inv_s;
    if (level == 0)      { f = f0 + (size_t)cl * P0; Hc = H0; Wc = W0; inv_s = 1.0f;  }
    else if (level == 1) { f = f1 + (size_t)cl * P1; Hc = H1; Wc = W1; inv_s = 0.5f;  }
    else                 { f = f2 + (size_t)cl * P2; Hc = H2; Wc = W2; inv_s = 0.25f; }
    float acc = 0.0f;
#pragma unroll
    for (int ry = 0; ry < 2; ++ry) {
        float Y = by1 + ((float)oh + 0.25f + 0.5f * ry) * bh;
        bool vy = (Y >= -1.0f) && (Y <= (float)H0);
        float Yc = fminf(fmaxf(Y, 0.0f), (float)(H0 - 1));
        int y0 = (int)Yc;
        float ly = Yc - (float)y0;
#pragma unroll
        for (int rx = 0; rx < 2; ++rx) {
            float X = bx1 + ((float)ow + 0.25f + 0.5f * rx) * bw;
            bool vx = (X >= -1.0f) && (X <= (float)W0);
            float Xc = fminf(fmaxf(X, 0.0f), (float)(W0 - 1));
            int x0 = (int)Xc;
            float lx = Xc - (float)x0;
            float v;
            if (level == 0) {
                int y1i = min(y0 + 1, H0 - 1), x1i = min(x0 + 1, W0 - 1);
                float hy = 1.0f - ly, hx = 1.0f - lx;
                float v00 = f[y0 * W0 + x0],  v01 = f[y0 * W0 + x1i];
                float v10 = f[y1i * W0 + x0], v11 = f[y1i * W0 + x1i];
                v = hy * (hx * v00 + lx * v01) + ly * (hx * v10 + lx * v11);
            } else {
                int yb, xb; float wy[3], wxl[3];
                axis_w3_fb(y0, H0, Hc, inv_s, ly, yb, wy);
                axis_w3_fb(x0, W0, Wc, inv_s, lx, xb, wxl);
                v = 0.0f;
#pragma unroll
                for (int a = 0; a < 3; ++a) {
                    int row = min(yb + a, Hc - 1) * Wc;
                    float s = 0.0f;
#pragma unroll
                    for (int b = 0; b < 3; ++b)
                        s += wxl[b] * f[row + min(xb + b, Wc - 1)];
                    v += wy[a] * s;
                }
            }
            if (vy && vx) acc += v;
        }
    }
    out[i] = acc * 0.25f;
}

// ---------------- launch ----------------------------------------------------
extern "C" void kernel_launch(void* const* d_in, const int* in_sizes, int n_in,
                              void* d_out, int out_size, void* d_ws, size_t ws_size,
                              hipStream_t stream) {
    const float* f0    = (const float*)d_in[0];
    const float* f1    = (const float*)d_in[1];
    const float* f2    = (const float*)d_in[2];
    const float* boxes = (const float*)d_in[3];
    const int* img_h_p = (const int*)d_in[4];
    const int* img_w_p = (const int*)d_in[5];
    float* out = (float*)d_out;
    int N = in_sizes[3] / 4;

    if (ws_size >= WS_BYTES) {
        unsigned short* ws = (unsigned short*)d_ws;
        unsigned short* T0 = ws + T0_OFF;
        unsigned short* T1 = ws + T1_OFF;
        unsigned short* T2 = ws + T2_OFF;
        int n0 = ((P0 + 63) / 64) * 4;   // 3800
        int n1 = ((P1 + 63) / 64) * 4;   // 952
        int n2 = ((P2 + 63) / 64) * 4;   // 240
        transpose_all_kernel<<<n0 + n1 + n2, 256, 0, stream>>>(
            f0, f1, f2, T0, T1, T2, n0, n0 + n1);
        roi_align_cl5_kernel<<<dim3(N, 3), 512, 0, stream>>>(
            T0, T1, T2, boxes, img_h_p, img_w_p, out);
    } else {
        int total = N * CTOT * OH * OW;
        roi_align_fused_fb_kernel<<<(total + 255) / 256, 256, 0, stream>>>(
            f0, f1, f2, boxes, img_h_p, img_w_p, out, total);
    }
}

// Round 9
// 160.921 us; speedup vs baseline: 1.0254x; 1.0254x over previous
//
#include <hip/hip_runtime.h>
#include <hip/hip_bf16.h>

#define H0 200
#define W0 304
#define H1 100
#define W1 152
#define H2 50
#define W2 76
#define CPL 256   // channels per level
#define CTOT 768
#define OH 7
#define OW 7
#define NPOS 49
#define SROW 264  // sout row stride (floats)

#define P0 (H0*W0)   // 60800
#define P1 (H1*W1)   // 15200
#define P2 (H2*W2)   // 3800
#define T0_OFF ((size_t)0)
#define T1_OFF ((size_t)P0*CPL)
#define T2_OFF ((size_t)P0*CPL + (size_t)P1*CPL)
#define WS_ELEMS ((size_t)P0*CPL + (size_t)P1*CPL + (size_t)P2*CPL)
#define WS_BYTES (WS_ELEMS * 2)   // bf16 workspace: 40,857,600 B

__device__ __forceinline__ float hat01(float d) {
    return fmaxf(0.0f, 1.0f - fabsf(d));
}

__device__ __forceinline__ unsigned short f2bf_rne(float x) {
    unsigned int u = __float_as_uint(x);
    u += 0x7fffu + ((u >> 16) & 1u);
    return (unsigned short)(u >> 16);
}

// ------------- Stage 1: fused [C][P] fp32 -> [P][C] bf16 transpose ----------
__global__ void __launch_bounds__(256)
transpose_all_kernel(const float* __restrict__ f0, const float* __restrict__ f1,
                     const float* __restrict__ f2,
                     unsigned short* __restrict__ T0,
                     unsigned short* __restrict__ T1,
                     unsigned short* __restrict__ T2, int n0, int n01) {
    __shared__ unsigned short tile[64][72];   // [p_local][c_local]
    int b = blockIdx.x;
    const float* in; unsigned short* outp; int P; int rel;
    if (b < n0)       { in = f0; outp = T0; P = P0; rel = b; }
    else if (b < n01) { in = f1; outp = T1; P = P1; rel = b - n0; }
    else              { in = f2; outp = T2; P = P2; rel = b - n01; }
    int p0 = (rel >> 2) * 64;
    int c0 = (rel & 3) * 64;

    int q = threadIdx.x & 15;     // p-quad
    int r = threadIdx.x >> 4;     // 0..15 (c)
    bool full = (p0 + 64 <= P);
#pragma unroll
    for (int i = 0; i < 4; ++i) {
        int c = c0 + r + 16 * i;
        int p = p0 + 4 * q;
        float4 v;
        if (full) {
            v = *(const float4*)(in + (size_t)c * P + p);
        } else {
            v.x = (p + 0 < P) ? in[(size_t)c * P + p + 0] : 0.0f;
            v.y = (p + 1 < P) ? in[(size_t)c * P + p + 1] : 0.0f;
            v.z = (p + 2 < P) ? in[(size_t)c * P + p + 2] : 0.0f;
            v.w = (p + 3 < P) ? in[(size_t)c * P + p + 3] : 0.0f;
        }
        tile[4 * q + 0][r + 16 * i] = f2bf_rne(v.x);
        tile[4 * q + 1][r + 16 * i] = f2bf_rne(v.y);
        tile[4 * q + 2][r + 16 * i] = f2bf_rne(v.z);
        tile[4 * q + 3][r + 16 * i] = f2bf_rne(v.w);
    }
    __syncthreads();
    int q8 = threadIdx.x & 7;     // c-octet
    int r8 = threadIdx.x >> 3;    // 0..31 (p)
#pragma unroll
    for (int i = 0; i < 2; ++i) {
        int p = p0 + r8 + 32 * i;
        if (p < P) {
            uint4 w = *(const uint4*)&tile[r8 + 32 * i][8 * q8];
            *(uint4*)(outp + (size_t)p * CPL + c0 + 8 * q8) = w;
        }
    }
}

// ------------- Stage 2: channels-last RoIAlign, bf16x8 per lane -------------
// Half-wave per position: lanes 0..31 -> pos 2*pp, lanes 32..63 -> pos 2*pp+1.
// Lane carries 8 channels (one uint4 = 16B per tap) -> 32 lanes cover all 256
// channels of the level. 25 pairs cover 49 positions (pair 24 half=1 clamps to
// pos 48: duplicate identical write, benign). Fixed compile-time tap counts.
template<int TY, int TX>
__device__ __forceinline__ void run_level_pair(const unsigned short* __restrict__ Tc,
                                               const int (*s_idx)[6], const float (*s_w)[6],
                                               float (*sout)[SROW], int wv, int half, int l) {
    for (int pp = wv; pp < 25; pp += 8) {
        int pos = 2 * pp + half;
        pos = (pos > NPOS - 1) ? (NPOS - 1) : pos;   // benign duplicate on tail
        int oh = pos / 7;
        int ow = pos - oh * 7;
        int yi[TY], xi[TX];
        float yw[TY], xw[TX];
#pragma unroll
        for (int j = 0; j < TY; ++j) { yi[j] = s_idx[oh][j];     yw[j] = s_w[oh][j]; }
#pragma unroll
        for (int j = 0; j < TX; ++j) { xi[j] = s_idx[7 + ow][j]; xw[j] = s_w[7 + ow][j]; }

        float a0 = 0.f, a1 = 0.f, a2 = 0.f, a3 = 0.f;
        float a4 = 0.f, a5 = 0.f, a6 = 0.f, a7 = 0.f;
#pragma unroll
        for (int a = 0; a < TY; ++a) {
            float s0 = 0.f, s1 = 0.f, s2 = 0.f, s3 = 0.f;
            float s4 = 0.f, s5 = 0.f, s6 = 0.f, s7 = 0.f;
#pragma unroll
            for (int b = 0; b < TX; ++b) {
                uint4 v = *(const uint4*)(Tc + (unsigned)(yi[a] + xi[b]));
                float wxb = xw[b];
                s0 += wxb * __uint_as_float(v.x << 16);
                s1 += wxb * __uint_as_float(v.x & 0xffff0000u);
                s2 += wxb * __uint_as_float(v.y << 16);
                s3 += wxb * __uint_as_float(v.y & 0xffff0000u);
                s4 += wxb * __uint_as_float(v.z << 16);
                s5 += wxb * __uint_as_float(v.z & 0xffff0000u);
                s6 += wxb * __uint_as_float(v.w << 16);
                s7 += wxb * __uint_as_float(v.w & 0xffff0000u);
            }
            float wya = yw[a];
            a0 += wya * s0; a1 += wya * s1; a2 += wya * s2; a3 += wya * s3;
            a4 += wya * s4; a5 += wya * s5; a6 += wya * s6; a7 += wya * s7;
        }
        float4 r0, r1;
        r0.x = a0 * 0.25f; r0.y = a1 * 0.25f; r0.z = a2 * 0.25f; r0.w = a3 * 0.25f;
        r1.x = a4 * 0.25f; r1.y = a5 * 0.25f; r1.z = a6 * 0.25f; r1.w = a7 * 0.25f;
        *(float4*)&sout[pos][8 * l + 0] = r0;
        *(float4*)&sout[pos][8 * l + 4] = r1;
    }
}

__global__ void __launch_bounds__(512)
roi_align_cl7_kernel(const unsigned short* __restrict__ T0,
                     const unsigned short* __restrict__ T1,
                     const unsigned short* __restrict__ T2,
                     const float* __restrict__ boxes,
                     const int* __restrict__ img_h_p,
                     const int* __restrict__ img_w_p,
                     float* __restrict__ out) {
    __shared__ float sout[NPOS][SROW];
    __shared__ int   s_idx[14][6];
    __shared__ float s_w[14][6];

    int n = blockIdx.x;
    int level = blockIdx.y;
    const unsigned short* T; int Hc, Wc; float inv_s;
    if (level == 0)      { T = T0; Hc = H0; Wc = W0; inv_s = 1.0f;  }
    else if (level == 1) { T = T1; Hc = H1; Wc = W1; inv_s = 0.5f;  }
    else                 { T = T2; Hc = H2; Wc = W2; inv_s = 0.25f; }

    int tid = threadIdx.x;
    if (tid < 14) {
        int axis = (tid >= 7) ? 1 : 0;   // 0 = y, 1 = x
        int o = tid - axis * 7;
        float sx = (float)W0 / (float)img_w_p[0];
        float sy = (float)H0 / (float)img_h_p[0];
        float a1, bs; int Hf, Hca, mul;
        if (axis) {
            a1 = boxes[n * 4 + 0] * sx;
            float a2 = boxes[n * 4 + 2] * sx;
            bs = fmaxf(a2 - a1, 1.0f) * (1.0f / (float)OW);
            Hf = W0; Hca = Wc; mul = 1;
        } else {
            a1 = boxes[n * 4 + 1] * sy;
            float a2 = boxes[n * 4 + 3] * sy;
            bs = fmaxf(a2 - a1, 1.0f) * (1.0f / (float)OH);
            Hf = H0; Hca = Hc; mul = Wc;
        }
        int idx[6]; float w[6];
#pragma unroll
        for (int j = 0; j < 6; ++j) { idx[j] = 0; w[j] = 0.0f; }
        if (level == 0) {
#pragma unroll
            for (int r2 = 0; r2 < 2; ++r2) {
                float Y = a1 + ((float)o + 0.25f + 0.5f * (float)r2) * bs;
                float v = (Y >= -1.0f && Y <= (float)Hf) ? 1.0f : 0.0f;
                float Yc = fminf(fmaxf(Y, 0.0f), (float)(Hf - 1));
                int y0 = (int)Yc; float lf = Yc - (float)y0;
                idx[2 * r2]     = y0;                  w[2 * r2]     = (1.0f - lf) * v;
                idx[2 * r2 + 1] = min(y0 + 1, Hf - 1); w[2 * r2 + 1] = lf * v;
            }
        } else {
            int bases[2]; float w3[2][3];
#pragma unroll
            for (int r2 = 0; r2 < 2; ++r2) {
                float Y = a1 + ((float)o + 0.25f + 0.5f * (float)r2) * bs;
                float v = (Y >= -1.0f && Y <= (float)Hf) ? 1.0f : 0.0f;
                float Yc = fminf(fmaxf(Y, 0.0f), (float)(Hf - 1));
                int y0 = (int)Yc; float lf = Yc - (float)y0; float hf = 1.0f - lf;
                int yf1 = min(y0 + 1, Hf - 1);
                float yc0 = fminf(fmaxf(((float)y0 + 0.5f) * inv_s - 0.5f, 0.0f), (float)(Hca - 1));
                float yc1 = fminf(fmaxf(((float)yf1 + 0.5f) * inv_s - 0.5f, 0.0f), (float)(Hca - 1));
                int b2 = (int)yc0;
                bases[r2] = b2;
#pragma unroll
                for (int t2 = 0; t2 < 3; ++t2) {
                    float j2 = (float)(b2 + t2);
                    w3[r2][t2] = v * (hf * hat01(yc0 - j2) + lf * hat01(yc1 - j2));
                }
            }
            int dmax = (level == 1) ? 3 : 2;   // geometry: box<=272px -> gap<=2.43/1.21
            int d = min(max(bases[1] - bases[0], 0), dmax);
            w[0] += w3[0][0]; w[1] += w3[0][1]; w[2] += w3[0][2];
            w[d] += w3[1][0]; w[d + 1] += w3[1][1]; w[d + 2] += w3[1][2];
#pragma unroll
            for (int j = 0; j < 6; ++j) idx[j] = min(bases[0] + j, Hca - 1);
        }
        // pre-scale to element offset (row stride incl. CPL; col stride = CPL)
#pragma unroll
        for (int j = 0; j < 6; ++j) { s_idx[tid][j] = idx[j] * mul * CPL; s_w[tid][j] = w[j]; }
    }
    __syncthreads();

    int lane = tid & 63;
    int wv = tid >> 6;                 // 0..7
    int half = (lane >> 5) & 1;        // half-wave -> even / odd pos of pair
    int l = lane & 31;                 // 0..31, 8 channels each
    const unsigned short* Tc = T + l * 8;

    if (level == 0)      run_level_pair<4, 4>(Tc, s_idx, s_w, sout, wv, half, l);
    else if (level == 1) run_level_pair<6, 6>(Tc, s_idx, s_w, sout, wv, half, l);
    else                 run_level_pair<5, 5>(Tc, s_idx, s_w, sout, wv, half, l);
    __syncthreads();

    size_t obase = ((size_t)n * CTOT + (size_t)level * CPL) * NPOS;
    for (int i2 = tid; i2 < CPL * NPOS; i2 += 512) {
        int c = i2 / NPOS;
        int p = i2 - c * NPOS;
        out[obase + i2] = sout[p][c];
    }
}

// ---------------- Fallback (R1 kernel) if ws too small ----------------------
__device__ __forceinline__ void axis_w3_fb(int yf0, int Hf, int Hc, float inv_s,
                                           float lf, int& base, float* w) {
    int yf1 = min(yf0 + 1, Hf - 1);
    float hf = 1.0f - lf;
    float yc0 = fminf(fmaxf(((float)yf0 + 0.5f) * inv_s - 0.5f, 0.0f), (float)(Hc - 1));
    float yc1 = fminf(fmaxf(((float)yf1 + 0.5f) * inv_s - 0.5f, 0.0f), (float)(Hc - 1));
    base = (int)yc0;
#pragma unroll
    for (int r = 0; r < 3; ++r) {
        float j = (float)(base + r);
        w[r] = hf * hat01(yc0 - j) + lf * hat01(yc1 - j);
    }
}

__global__ void __launch_bounds__(256)
roi_align_fused_fb_kernel(const float* __restrict__ f0,
                          const float* __restrict__ f1,
                          const float* __restrict__ f2,
                          const float* __restrict__ boxes,
                          const int* __restrict__ img_h_p,
                          const int* __restrict__ img_w_p,
                          float* __restrict__ out,
                          int total) {
    int i = blockIdx.x * blockDim.x + threadIdx.x;
    if (i >= total) return;
    int ow = i % OW;
    int t = i / OW;
    int oh = t % OH; t /= OH;
    int c = t % CTOT;
    int n = t / CTOT;
    float sx = (float)W0 / (float)img_w_p[0];
    float sy = (float)H0 / (float)img_h_p[0];
    float bx1 = boxes[n * 4 + 0] * sx;
    float by1 = boxes[n * 4 + 1] * sy;
    float bw = fmaxf(boxes[n * 4 + 2] * sx - bx1, 1.0f) / OW;
    float bh = fmaxf(boxes[n * 4 + 3] * sy - by1, 1.0f) / OH;
    int level = c >> 8;
    int cl = c & (CPL - 1);
    const float* f;
    int Hc, Wc; float inv_s;
    if (level == 0)      { f = f0 + (size_t)cl * P0; Hc = H0; Wc = W0; inv_s = 1.0f;  }
    else if (level == 1) { f = f1 + (size_t)cl * P1; Hc = H1; Wc = W1; inv_s = 0.5f;  }
    else                 { f = f2 + (size_t)cl * P2; Hc = H2; Wc = W2; inv_s = 0.25f; }
    float acc = 0.0f;
#pragma unroll
    for (int ry = 0; ry < 2; ++ry) {
        float Y = by1 + ((float)oh + 0.25f + 0.5f * ry) * bh;
        bool vy = (Y >= -1.0f) && (Y <= (float)H0);
        float Yc = fminf(fmaxf(Y, 0.0f), (float)(H0 - 1));
        int y0 = (int)Yc;
        float ly = Yc - (float)y0;
#pragma unroll
        for (int rx = 0; rx < 2; ++rx) {
            float X = bx1 + ((float)ow + 0.25f + 0.5f * rx) * bw;
            bool vx = (X >= -1.0f) && (X <= (float)W0);
            float Xc = fminf(fmaxf(X, 0.0f), (float)(W0 - 1));
            int x0 = (int)Xc;
            float lx = Xc - (float)x0;
            float v;
            if (level == 0) {
                int y1i = min(y0 + 1, H0 - 1), x1i = min(x0 + 1, W0 - 1);
                float hy = 1.0f - ly, hx = 1.0f - lx;
                float v00 = f[y0 * W0 + x0],  v01 = f[y0 * W0 + x1i];
                float v10 = f[y1i * W0 + x0], v11 = f[y1i * W0 + x1i];
                v = hy * (hx * v00 + lx * v01) + ly * (hx * v10 + lx * v11);
            } else {
                int yb, xb; float wy[3], wxl[3];
                axis_w3_fb(y0, H0, Hc, inv_s, ly, yb, wy);
                axis_w3_fb(x0, W0, Wc, inv_s, lx, xb, wxl);
                v = 0.0f;
#pragma unroll
                for (int a = 0; a < 3; ++a) {
                    int row = min(yb + a, Hc - 1) * Wc;
                    float s = 0.0f;
#pragma unroll
                    for (int b = 0; b < 3; ++b)
                        s += wxl[b] * f[row + min(xb + b, Wc - 1)];
                    v += wy[a] * s;
                }
            }
            if (vy && vx) acc += v;
        }
    }
    out[i] = acc * 0.25f;
}

// ---------------- launch ----------------------------------------------------
extern "C" void kernel_launch(void* const* d_in, const int* in_sizes, int n_in,
                              void* d_out, int out_size, void* d_ws, size_t ws_size,
                              hipStream_t stream) {
    const float* f0    = (const float*)d_in[0];
    const float* f1    = (const float*)d_in[1];
    const float* f2    = (const float*)d_in[2];
    const float* boxes = (const float*)d_in[3];
    const int* img_h_p = (const int*)d_in[4];
    const int* img_w_p = (const int*)d_in[5];
    float* out = (float*)d_out;
    int N = in_sizes[3] / 4;

    if (ws_size >= WS_BYTES) {
        unsigned short* ws = (unsigned short*)d_ws;
        unsigned short* T0 = ws + T0_OFF;
        unsigned short* T1 = ws + T1_OFF;
        unsigned short* T2 = ws + T2_OFF;
        int n0 = ((P0 + 63) / 64) * 4;   // 3800
        int n1 = ((P1 + 63) / 64) * 4;   // 952
        int n2 = ((P2 + 63) / 64) * 4;   // 240
        transpose_all_kernel<<<n0 + n1 + n2, 256, 0, stream>>>(
            f0, f1, f2, T0, T1, T2, n0, n0 + n1);
        roi_align_cl7_kernel<<<dim3(N, 3), 512, 0, stream>>>(
            T0, T1, T2, boxes, img_h_p, img_w_p, out);
    } else {
        int total = N * CTOT * OH * OW;
        roi_align_fused_fb_kernel<<<(total + 255) / 256, 256, 0, stream>>>(
            f0, f1, f2, boxes, img_h_p, img_w_p, out, total);
    }
}